// Round 1
// baseline (43135.321 us; speedup 1.0000x reference)
//
#include <hip/hip_runtime.h>
#include <hip/hip_cooperative_groups.h>

namespace cg = cooperative_groups;

#define SEQ 1024

typedef __bf16 bf16x8 __attribute__((ext_vector_type(8)));
typedef float f32x4 __attribute__((ext_vector_type(4)));
typedef unsigned int u32x4 __attribute__((ext_vector_type(4)));

__device__ __forceinline__ unsigned short f32_bf16_rne(float f) {
  unsigned u = __float_as_uint(f);
  unsigned r = u + 0x7fffu + ((u >> 16) & 1u);
  return (unsigned short)(r >> 16);
}
__device__ __forceinline__ float bf16_f32(unsigned short h) {
  return __uint_as_float(((unsigned)h) << 16);
}
__device__ __forceinline__ bf16x8 ldb16(const unsigned short* p) {
  u32x4 v = *reinterpret_cast<const u32x4*>(p);
  return __builtin_bit_cast(bf16x8, v);
}
__device__ __forceinline__ unsigned cvtpk(float a, float b) {
  unsigned r;
  asm("v_cvt_pk_bf16_f32 %0, %1, %2" : "=v"(r) : "v"(a), "v"(b));
  return r;
}
__device__ __forceinline__ bf16x8 cvt8(const float* p) {
  f32x4 v0 = *reinterpret_cast<const f32x4*>(p);
  f32x4 v1 = *reinterpret_cast<const f32x4*>(p + 4);
  u32x4 r;
  r.x = cvtpk(v0.x, v0.y); r.y = cvtpk(v0.z, v0.w);
  r.z = cvtpk(v1.x, v1.y); r.w = cvtpk(v1.z, v1.w);
  return __builtin_bit_cast(bf16x8, r);
}
__device__ __forceinline__ float sigf(float v) { return 1.0f / (1.0f + __expf(-v)); }
__device__ __forceinline__ float tanhf_(float v) { return 1.0f - 2.0f / (1.0f + __expf(2.0f * v)); }

#define MFMA(a, b, c) __builtin_amdgcn_mfma_f32_16x16x32_bf16(a, b, c, 0, 0, 0)

// Permute + hi/lo-split weights into per-wave-contiguous 1KB fragment blocks.
// wp layout: [(layer*64+wgi)][ks(32)][nt(2)][hs(2)][lane(64)][8 u16]
__global__ __launch_bounds__(256) void lstm_prep(const float* __restrict__ W0,
                                                 const float* __restrict__ W1,
                                                 unsigned short* __restrict__ wp) {
  int gid = blockIdx.x * 256 + threadIdx.x;  // 524288 total
  int lane = gid & 63;
  int r = gid >> 6;
  int nt = r & 1;  r >>= 1;
  int ks = r & 31; r >>= 5;
  int wgi = r & 63; r >>= 6;
  int layer = r;  // 0..1
  const float* W = layer ? W1 : W0;
  int l15 = lane & 15, l4 = lane >> 4;
  int nloc = nt * 16 + l15;                       // 0..31 within WG
  int grow = (nloc >> 3) * 512 + wgi * 8 + (nloc & 7);  // gate*512 + hcol
  int kb = ks * 32 + l4 * 8;
  const float* src = W + (size_t)grow * 1024 + kb;
  alignas(16) unsigned short hi[8];
  alignas(16) unsigned short lo[8];
#pragma unroll
  for (int j = 0; j < 8; ++j) {
    float v = src[j];
    unsigned short h = f32_bf16_rne(v);
    hi[j] = h;
    lo[j] = f32_bf16_rne(v - bf16_f32(h));
  }
  size_t base = ((((size_t)(layer * 64 + wgi) * 32 + ks) * 2 + nt) * 2) * 512 + (size_t)lane * 8;
  *reinterpret_cast<u32x4*>(wp + base)       = *reinterpret_cast<const u32x4*>(hi);
  *reinterpret_cast<u32x4*>(wp + base + 512) = *reinterpret_cast<const u32x4*>(lo);
}

// Persistent cooperative kernel: 128 WGs (layer = wg>>6, hcols [wgi*8, wgi*8+8)).
// Wave q owns K-quarter q. Pipelined: phase p runs layer0 step p and layer1 step p-1.
__global__ __launch_bounds__(256) void lstm_main(
    const float* __restrict__ x,
    const float* __restrict__ b0, const float* __restrict__ b1,
    const unsigned short* __restrict__ wp,
    unsigned short* hbuf,      // [4][64][512] bf16: l0p0,l0p1,l1p0,l1p1
    float* __restrict__ out) {
  __shared__ float zbuf[4][64][33];
  const int wg = blockIdx.x;
  const int layer = wg >> 6;
  const int wgi = wg & 63;
  const int tid = threadIdx.x;
  const int q = tid >> 6;
  const int l = tid & 63;
  const int l15 = l & 15, l4 = l >> 4;
  const int hc = tid & 7;

  cg::grid_group grid = cg::this_grid();

  const float* bias = layer ? b1 : b0;
  float bi[4];
#pragma unroll
  for (int g = 0; g < 4; ++g) bi[g] = bias[g * 512 + wgi * 8 + hc];

  float c0 = 0.0f, c1 = 0.0f;
  const unsigned short* wpb = wp + (size_t)(layer * 64 + wgi) * 65536 + (size_t)l * 8;

  for (int p = 0; p <= SEQ; ++p) {
    const bool active = (layer == 0) ? (p < SEQ) : (p >= 1);
    const int t = (layer == 0) ? p : p - 1;
    const int cu = t & 1, pr = (t + 1) & 1;
    if (active) {
      f32x4 acc[4][2];
#pragma unroll
      for (int mt = 0; mt < 4; ++mt) { acc[mt][0] = 0.0f; acc[mt][1] = 0.0f; }
#pragma unroll
      for (int ks8 = 0; ks8 < 8; ++ks8) {
        const int ks = q * 8 + ks8;
        const int kb = ks * 32 + l4 * 8;
        const unsigned short* wk = wpb + ks * 2048;
        bf16x8 bh0 = ldb16(wk);
        bf16x8 bl0 = ldb16(wk + 512);
        bf16x8 bh1 = ldb16(wk + 1024);
        bf16x8 bl1 = ldb16(wk + 1536);
        bf16x8 a[4];
#pragma unroll
        for (int mt = 0; mt < 4; ++mt) {
          const int row = mt * 16 + l15;
          if (layer == 0) {
            if (kb < 512) a[mt] = cvt8(x + ((size_t)t << 15) + row * 512 + kb);
            else          a[mt] = ldb16(hbuf + pr * 32768 + row * 512 + (kb - 512));
          } else {
            if (kb < 512) a[mt] = ldb16(hbuf + cu * 32768 + row * 512 + kb);
            else          a[mt] = ldb16(hbuf + (2 + pr) * 32768 + row * 512 + (kb - 512));
          }
        }
#pragma unroll
        for (int mt = 0; mt < 4; ++mt) {
          acc[mt][0] = MFMA(a[mt], bh0, acc[mt][0]);
          acc[mt][0] = MFMA(a[mt], bl0, acc[mt][0]);
          acc[mt][1] = MFMA(a[mt], bh1, acc[mt][1]);
          acc[mt][1] = MFMA(a[mt], bl1, acc[mt][1]);
        }
      }
#pragma unroll
      for (int mt = 0; mt < 4; ++mt)
#pragma unroll
        for (int nt = 0; nt < 2; ++nt)
#pragma unroll
          for (int r = 0; r < 4; ++r)
            zbuf[q][mt * 16 + l4 * 4 + r][nt * 16 + l15] = acc[mt][nt][r];
    }
    __syncthreads();
    if (active) {
#pragma unroll
      for (int e = 0; e < 2; ++e) {
        const int pid = (e << 8) | tid;
        const int b = pid >> 3;
        float z[4];
#pragma unroll
        for (int g = 0; g < 4; ++g) {
          float s = bi[g];
#pragma unroll
          for (int qq = 0; qq < 4; ++qq) s += zbuf[qq][b][g * 8 + hc];
          z[g] = s;
        }
        const float si = sigf(z[0]), sf = sigf(z[1]), so = sigf(z[2]), tg = tanhf_(z[3]);
        float c = (e ? c1 : c0);
        c = sf * c + si * tg;
        if (e) c1 = c; else c0 = c;
        const float h = so * tanhf_(c);
        const size_t bo = (size_t)b * 512 + (size_t)(wgi * 8 + hc);
        if (layer == 0) {
          hbuf[cu * 32768 + bo] = f32_bf16_rne(h);
          if (t == SEQ - 1) { out[33554432 + bo] = h; out[33619968 + bo] = c; }
        } else {
          hbuf[(2 + cu) * 32768 + bo] = f32_bf16_rne(h);
          out[((size_t)t << 15) + bo] = h;
          if (t == SEQ - 1) { out[33554432 + 32768 + bo] = h; out[33619968 + 32768 + bo] = c; }
        }
      }
      __threadfence();
    }
    grid.sync();
  }
}

extern "C" void kernel_launch(void* const* d_in, const int* in_sizes, int n_in,
                              void* d_out, int out_size, void* d_ws, size_t ws_size,
                              hipStream_t stream) {
  const float* x  = (const float*)d_in[0];
  const float* W0 = (const float*)d_in[1];
  const float* b0 = (const float*)d_in[2];
  const float* W1 = (const float*)d_in[3];
  const float* b1 = (const float*)d_in[4];
  float* out = (float*)d_out;

  unsigned short* wp   = (unsigned short*)d_ws;   // 16 MB split weights
  unsigned short* hbuf = wp + 8388608;            // 256 KB h double-buffers

  hipMemsetAsync(hbuf, 0, 262144, stream);
  lstm_prep<<<2048, 256, 0, stream>>>(W0, W1, wp);

  void* args[] = { (void*)&x, (void*)&b0, (void*)&b1, (void*)&wp, (void*)&hbuf, (void*)&out };
  hipLaunchCooperativeKernel((void*)lstm_main, dim3(128), dim3(256), args, 0, stream);
}

// Round 2
// 26234.283 us; speedup vs baseline: 1.6442x; 1.6442x over previous
//
#include <hip/hip_runtime.h>

#define SEQ 1024

typedef __bf16 bf16x8 __attribute__((ext_vector_type(8)));
typedef float f32x4 __attribute__((ext_vector_type(4)));
typedef unsigned int u32x4 __attribute__((ext_vector_type(4)));
typedef unsigned long long u64;

__device__ __forceinline__ unsigned short f32_bf16_rne(float f) {
  unsigned u = __float_as_uint(f);
  unsigned r = u + 0x7fffu + ((u >> 16) & 1u);
  return (unsigned short)(r >> 16);
}
__device__ __forceinline__ float bf16_f32(unsigned short h) {
  return __uint_as_float(((unsigned)h) << 16);
}
__device__ __forceinline__ bf16x8 ldb16(const unsigned short* p) {
  u32x4 v = *reinterpret_cast<const u32x4*>(p);
  return __builtin_bit_cast(bf16x8, v);
}
// Agent-scope relaxed atomic load pair: global_load_dwordx2 sc1 -> bypasses the
// (non-cross-XCD-coherent) L2, reads fresh from MALL. No cache invalidate needed.
__device__ __forceinline__ bf16x8 lda_h(const unsigned short* p) {
  u64* q = (u64*)p;
  u64 a = __hip_atomic_load(q,     __ATOMIC_RELAXED, __HIP_MEMORY_SCOPE_AGENT);
  u64 b = __hip_atomic_load(q + 1, __ATOMIC_RELAXED, __HIP_MEMORY_SCOPE_AGENT);
  u64 v2[2] = {a, b};
  return __builtin_bit_cast(bf16x8, *reinterpret_cast<u32x4*>(v2));
}
__device__ __forceinline__ unsigned cvtpk(float a, float b) {
  unsigned r;
  asm("v_cvt_pk_bf16_f32 %0, %1, %2" : "=v"(r) : "v"(a), "v"(b));
  return r;
}
__device__ __forceinline__ bf16x8 cvt8(const float* p) {
  f32x4 v0 = *reinterpret_cast<const f32x4*>(p);
  f32x4 v1 = *reinterpret_cast<const f32x4*>(p + 4);
  u32x4 r;
  r.x = cvtpk(v0.x, v0.y); r.y = cvtpk(v0.z, v0.w);
  r.z = cvtpk(v1.x, v1.y); r.w = cvtpk(v1.z, v1.w);
  return __builtin_bit_cast(bf16x8, r);
}
__device__ __forceinline__ float sigf(float v) { return 1.0f / (1.0f + __expf(-v)); }
__device__ __forceinline__ float tanhf_(float v) { return 1.0f - 2.0f / (1.0f + __expf(2.0f * v)); }
__device__ __forceinline__ void spin_ge(int* c, int v) {
  while (__hip_atomic_load(c, __ATOMIC_RELAXED, __HIP_MEMORY_SCOPE_AGENT) < v)
    __builtin_amdgcn_s_sleep(1);
}

#define MFMA(a, b, c) __builtin_amdgcn_mfma_f32_16x16x32_bf16(a, b, c, 0, 0, 0)

// Permute + hi/lo-split weights into per-wave-contiguous 1KB fragment blocks.
// wp layout: [(layer*64+wgi)][ks(32)][nt(2)][hs(2)][lane(64)][8 u16]
__global__ __launch_bounds__(256) void lstm_prep(const float* __restrict__ W0,
                                                 const float* __restrict__ W1,
                                                 unsigned short* __restrict__ wp) {
  int gid = blockIdx.x * 256 + threadIdx.x;  // 524288 total
  int lane = gid & 63;
  int r = gid >> 6;
  int nt = r & 1;  r >>= 1;
  int ks = r & 31; r >>= 5;
  int wgi = r & 63; r >>= 6;
  int layer = r;  // 0..1
  const float* W = layer ? W1 : W0;
  int l15 = lane & 15, l4 = lane >> 4;
  int nloc = nt * 16 + l15;                       // 0..31 within WG
  int grow = (nloc >> 3) * 512 + wgi * 8 + (nloc & 7);  // gate*512 + hcol
  int kb = ks * 32 + l4 * 8;
  const float* src = W + (size_t)grow * 1024 + kb;
  alignas(16) unsigned short hi[8];
  alignas(16) unsigned short lo[8];
#pragma unroll
  for (int j = 0; j < 8; ++j) {
    float v = src[j];
    unsigned short h = f32_bf16_rne(v);
    hi[j] = h;
    lo[j] = f32_bf16_rne(v - bf16_f32(h));
  }
  size_t base = ((((size_t)(layer * 64 + wgi) * 32 + ks) * 2 + nt) * 2) * 512 + (size_t)lane * 8;
  *reinterpret_cast<u32x4*>(wp + base)       = *reinterpret_cast<const u32x4*>(hi);
  *reinterpret_cast<u32x4*>(wp + base + 512) = *reinterpret_cast<const u32x4*>(lo);
}

// Persistent kernel, event-driven pipeline. 128 WGs: layer = wg>>6, hcols
// [wgi*8, wgi*8+8). No grid.sync (its L2 invalidate evicted weights every
// phase). h exchanged via sc1 agent atomics through MALL; weights stay in L2.
// hbuf ring: [layer(2)][slot(4)][64 rows][512 cols] bf16.
__global__ __launch_bounds__(256) void lstm_main(
    const float* __restrict__ x,
    const float* __restrict__ b0, const float* __restrict__ b1,
    const unsigned short* __restrict__ wp,
    unsigned short* hbuf,
    int* cnt0, int* cnt1,
    float* __restrict__ out) {
  __shared__ float zbuf[4][64][33];
  const int wg = blockIdx.x;
  const int layer = wg >> 6;
  const int wgi = wg & 63;
  const int tid = threadIdx.x;
  const int q = tid >> 6;
  const int l = tid & 63;
  const int l15 = l & 15, l4 = l >> 4;

  const float* bias = layer ? b1 : b0;
  // Epilogue: tid<128, thread owns (b=tid>>1, quad=tid&1) -> 4 consecutive cols.
  const int eb = tid >> 1, equad = tid & 1;
  float bi[4][4];
  if (tid < 128) {
#pragma unroll
    for (int g = 0; g < 4; ++g)
#pragma unroll
      for (int j = 0; j < 4; ++j)
        bi[g][j] = bias[g * 512 + wgi * 8 + equad * 4 + j];
  }
  float cst[4] = {0.0f, 0.0f, 0.0f, 0.0f};

  const unsigned short* wpb = wp + (size_t)(layer * 64 + wgi) * 65536 + (size_t)l * 8;

  for (int t = 0; t < SEQ; ++t) {
    // ---- wait for producers (thread 0 spins, others park at barrier) ----
    if (tid == 0) {
      if (layer == 0) {
        if (t > 0)  spin_ge(cnt0 + t - 1, 64);
        if (t >= 4) spin_ge(cnt1 + t - 4, 64);   // ring back-pressure
      } else {
        spin_ge(cnt0 + t, 64);
        if (t > 0) spin_ge(cnt1 + t - 1, 64);
      }
    }
    __syncthreads();

    const unsigned short* h0p = hbuf + (((t - 1) & 3) << 15);        // h0[t-1]
    const unsigned short* h0c = hbuf + ((t & 3) << 15);              // h0[t]
    const unsigned short* h1p = hbuf + ((4 + ((t - 1) & 3)) << 15);  // h1[t-1]

    // ---- GEMM: wave q owns K-quarter q ----
    f32x4 acc[4][2];
#pragma unroll
    for (int mt = 0; mt < 4; ++mt) { acc[mt][0] = 0.0f; acc[mt][1] = 0.0f; }
#pragma unroll
    for (int ks8 = 0; ks8 < 8; ++ks8) {
      const int ks = q * 8 + ks8;
      const int kb = ks * 32 + l4 * 8;
      const unsigned short* wk = wpb + ks * 2048;
      bf16x8 bh0 = ldb16(wk);
      bf16x8 bl0 = ldb16(wk + 512);
      bf16x8 bh1 = ldb16(wk + 1024);
      bf16x8 bl1 = ldb16(wk + 1536);
      bf16x8 a[4];
#pragma unroll
      for (int mt = 0; mt < 4; ++mt) {
        const int row = mt * 16 + l15;
        if (layer == 0) {
          if (kb < 512) a[mt] = cvt8(x + ((size_t)t << 15) + row * 512 + kb);
          else          a[mt] = lda_h(h0p + row * 512 + (kb - 512));
        } else {
          if (kb < 512) a[mt] = lda_h(h0c + row * 512 + kb);
          else          a[mt] = lda_h(h1p + row * 512 + (kb - 512));
        }
      }
#pragma unroll
      for (int mt = 0; mt < 4; ++mt) {
        acc[mt][0] = MFMA(a[mt], bh0, acc[mt][0]);
        acc[mt][0] = MFMA(a[mt], bl0, acc[mt][0]);
        acc[mt][1] = MFMA(a[mt], bh1, acc[mt][1]);
        acc[mt][1] = MFMA(a[mt], bl1, acc[mt][1]);
      }
    }
#pragma unroll
    for (int mt = 0; mt < 4; ++mt)
#pragma unroll
      for (int nt = 0; nt < 2; ++nt)
#pragma unroll
        for (int r = 0; r < 4; ++r)
          zbuf[q][mt * 16 + l4 * 4 + r][nt * 16 + l15] = acc[mt][nt][r];
    __syncthreads();

    // ---- epilogue: gates, c/h update, publish h ----
    if (tid < 128) {
      float hv[4];
#pragma unroll
      for (int j = 0; j < 4; ++j) {
        const int cl = equad * 4 + j;
        float z[4];
#pragma unroll
        for (int g = 0; g < 4; ++g) {
          float s = bi[g][j];
#pragma unroll
          for (int qq = 0; qq < 4; ++qq) s += zbuf[qq][eb][g * 8 + cl];
          z[g] = s;
        }
        float c = sigf(z[1]) * cst[j] + sigf(z[0]) * tanhf_(z[3]);
        cst[j] = c;
        hv[j] = sigf(z[2]) * tanhf_(c);
      }
      alignas(8) unsigned short hp[4];
#pragma unroll
      for (int j = 0; j < 4; ++j) hp[j] = f32_bf16_rne(hv[j]);
      const int col0 = wgi * 8 + equad * 4;
      unsigned short* hdst = hbuf + ((layer * 4 + (t & 3)) << 15) + eb * 512 + col0;
      __hip_atomic_store((u64*)hdst, *reinterpret_cast<u64*>(hp),
                         __ATOMIC_RELAXED, __HIP_MEMORY_SCOPE_AGENT);
      if (layer == 1) {
        f32x4 ov = {hv[0], hv[1], hv[2], hv[3]};
        *reinterpret_cast<f32x4*>(out + ((size_t)t << 15) + eb * 512 + col0) = ov;
      }
      if (t == SEQ - 1) {
        f32x4 hf = {hv[0], hv[1], hv[2], hv[3]};
        f32x4 cf = {cst[0], cst[1], cst[2], cst[3]};
        *reinterpret_cast<f32x4*>(out + 33554432 + layer * 32768 + eb * 512 + col0) = hf;
        *reinterpret_cast<f32x4*>(out + 33619968 + layer * 32768 + eb * 512 + col0) = cf;
      }
    }
    asm volatile("s_waitcnt vmcnt(0)" ::: "memory");  // h stores acked at MALL
    __syncthreads();
    if (tid == 0)
      __hip_atomic_fetch_add((layer == 0 ? cnt0 : cnt1) + t, 1,
                             __ATOMIC_RELEASE, __HIP_MEMORY_SCOPE_AGENT);
  }
}

extern "C" void kernel_launch(void* const* d_in, const int* in_sizes, int n_in,
                              void* d_out, int out_size, void* d_ws, size_t ws_size,
                              hipStream_t stream) {
  const float* x  = (const float*)d_in[0];
  const float* W0 = (const float*)d_in[1];
  const float* b0 = (const float*)d_in[2];
  const float* W1 = (const float*)d_in[3];
  const float* b1 = (const float*)d_in[4];
  float* out = (float*)d_out;

  unsigned short* wp   = (unsigned short*)d_ws;   // 16 MB split weights
  unsigned short* hbuf = wp + 8388608;            // 512 KB h rings (2 layers x 4 slots)
  int* cnt0 = (int*)(hbuf + 262144);              // 4 KB
  int* cnt1 = cnt0 + 1024;                        // 4 KB

  hipMemsetAsync(hbuf, 0, 524288 + 8192, stream);
  lstm_prep<<<2048, 256, 0, stream>>>(W0, W1, wp);

  void* args[] = { (void*)&x, (void*)&b0, (void*)&b1, (void*)&wp, (void*)&hbuf,
                   (void*)&cnt0, (void*)&cnt1, (void*)&out };
  hipLaunchCooperativeKernel((void*)lstm_main, dim3(128), dim3(256), args, 0, stream);
}